// Round 1
// baseline (57987.347 us; speedup 1.0000x reference)
//
#include <hip/hip_runtime.h>

// GRU scan, persistent cooperative kernel.
// 16 clusters x 64 batch rows; 16 blocks/cluster; block owns 32 hidden
// positions (96 gate rows). W' = [w_hh | w_ih | 0] (K=544) in f16, XOR-swizzled
// LDS. h exchanged via workspace with per-cluster device-scope atomic barrier.

#define NB    256
#define NT    128
#define TB    1024            // batch
#define TT    2048            // time
#define II    12
#define HH    512
#define KA    544             // 512 h + 12 x + 20 pad
#define GBLK  16              // blocks per cluster
#define ROWS  64              // rows per cluster
#define WSTRIDE 1152          // LDS row stride (bytes), mult of 128 for swizzle
#define LDSB  (96 * WSTRIDE)  // 110592 B
#define BUFELEMS (TB * KA)
#define BAR_OFF  ((size_t)2 * TB * KA * 2)   // bytes into ws
#define WS_USED  (BAR_OFF + 1024)

typedef _Float16 half8 __attribute__((ext_vector_type(8)));
typedef float    f32x4 __attribute__((ext_vector_type(4)));

__device__ __forceinline__ float fast_sigmoid(float x) {
  float e = exp2f(-1.44269504f * x);
  return __builtin_amdgcn_rcpf(1.0f + e);
}
__device__ __forceinline__ float fast_tanh(float x) {
  float e = exp2f(2.88539008f * x);           // exp(2x)
  return 1.0f - 2.0f * __builtin_amdgcn_rcpf(1.0f + e);
}

__global__ void __launch_bounds__(NT, 1)
gru_persistent(const float* __restrict__ hist,
               const float* __restrict__ w_ih,
               const float* __restrict__ w_hh,
               const float* __restrict__ w_out,
               const float* __restrict__ b_out,
               float* __restrict__ out,
               _Float16* __restrict__ buf,
               unsigned* __restrict__ bar)
{
  extern __shared__ char smem[];
  const int bid = blockIdx.x;
  const int c   = bid & 15;          // cluster (bid%16 -> spreads cluster over XCDs evenly)
  const int g   = bid >> 4;          // block within cluster, 0..15
  const int tid = threadIdx.x;
  const int wv  = tid >> 6;          // wave 0/1 (N-half)
  const int l   = tid & 63;
  const int l15 = l & 15;
  const int l4  = l >> 4;
  const int crb = c * ROWS;
  unsigned* mybar = bar + c * 16;    // 64B-spaced counters

  // ---- fill W' LDS: local row j = 48*h1 + 16*gate + pl ; global R = gate*512 + g*32 + h1*16 + pl
  for (int idx = tid; idx < 96 * (KA / 8); idx += NT) {
    const int j   = idx / (KA / 8);
    const int k8  = (idx - j * (KA / 8)) * 8;
    const int h1  = j / 48;
    const int r48 = j - h1 * 48;
    const int gt  = r48 >> 4;
    const int pl  = r48 & 15;
    const int R   = gt * 512 + g * 32 + h1 * 16 + pl;
    half8 v;
#pragma unroll
    for (int i = 0; i < 8; ++i) {
      const int k = k8 + i;
      float f = 0.0f;
      if (k < 512)                     f = w_hh[R * HH + k];
      else if (k < 524 && gt < 2)      f = w_ih[R * II + (k - 512)];   // n-gate x-part stays 0
      v[i] = (_Float16)f;
    }
    *(half8*)(smem + j * WSTRIDE + ((2 * k8) ^ ((j & 7) << 4))) = v;
  }

  // ---- persistent per-lane B-fragment for the i_n MFMA (w_ih n-rows, K window = x cols)
  half8 wihn;
  {
    const int R = 1024 + g * 32 + wv * 16 + l15;
#pragma unroll
    for (int i = 0; i < 8; ++i) {
      const int k = l4 * 8 + i;
      wihn[i] = (_Float16)((k < II) ? w_ih[R * II + k] : 0.0f);
    }
  }

  _Float16* buf0 = buf;
  _Float16* buf1 = buf + BUFELEMS;

  // ---- bootstrap: x_0 into buf0 x-region (h-region is memset-zero = h0)
  if (tid < 48) {
    const int r = tid / 12, i = tid - r * 12;
    const int row = crb + g * 4 + r;
    buf0[row * KA + 512 + i] = (_Float16)hist[(size_t)row * (TT * II) + i];
  }

  float hprev[4][4];
#pragma unroll
  for (int mt = 0; mt < 4; ++mt)
#pragma unroll
    for (int q = 0; q < 4; ++q) hprev[mt][q] = 0.0f;

  const int pcol = g * 32 + wv * 16 + l15;   // hidden index owned by this lane

  int deadlock = 0;
  // barrier 0 (x_0 visible; LDS fill synced by the __syncthreads below)
  __threadfence();
  __syncthreads();
  if (tid == 0) {
    __hip_atomic_fetch_add(mybar, 1u, __ATOMIC_RELEASE, __HIP_MEMORY_SCOPE_AGENT);
    long spin = 0;
    while (!deadlock &&
           __hip_atomic_load(mybar, __ATOMIC_ACQUIRE, __HIP_MEMORY_SCOPE_AGENT) < (unsigned)GBLK) {
      if (++spin > (1L << 24)) deadlock = 1;
    }
  }
  __syncthreads();

  for (int t = 0; t < TT; ++t) {
    const _Float16* bA = (t & 1) ? buf1 : buf0;   // A(t) = [h(t) | x_t | 0]
    _Float16*       bW = (t & 1) ? buf0 : buf1;   // receives h(t+1), x_{t+1}

    // ---- logits for step t-1 (h(t) = bA h-part); 4 rows/block, 4 dots/wave
    if (t > 0) {
      const int rr  = 2 * wv + (l >> 5);
      const int row = crb + g * 4 + rr;
      const int jj  = (l >> 4) & 1;
      const _Float16* hp = bA + row * KA + l15 * 32;
      const float*    wo = w_out + jj * HH + l15 * 32;
      float s = 0.0f;
#pragma unroll
      for (int c8 = 0; c8 < 4; ++c8) {
        half8 hv = *(const half8*)(hp + c8 * 8);
#pragma unroll
        for (int i = 0; i < 8; ++i) s += (float)hv[i] * wo[c8 * 8 + i];
      }
#pragma unroll
      for (int off = 1; off < 16; off <<= 1) s += __shfl_xor(s, off);
      if (l15 == 0) out[((size_t)row * TT + (t - 1)) * 2 + jj] = s + b_out[jj];
    }

    // ---- MFMA: acc[mt][0..2] = (r,z,n) pre-activations ; accin = i_n
    f32x4 acc[4][3];
    f32x4 accin[4];
#pragma unroll
    for (int mt = 0; mt < 4; ++mt) {
      accin[mt] = (f32x4){0.f, 0.f, 0.f, 0.f};
#pragma unroll
      for (int nt = 0; nt < 3; ++nt) acc[mt][nt] = (f32x4){0.f, 0.f, 0.f, 0.f};
    }
#pragma unroll
    for (int ks = 0; ks < 17; ++ks) {
      half8 a[4];
#pragma unroll
      for (int mt = 0; mt < 4; ++mt)
        a[mt] = *(const half8*)(bA + (crb + mt * 16 + l15) * KA + ks * 32 + l4 * 8);
      half8 bf[3];
#pragma unroll
      for (int nt = 0; nt < 3; ++nt) {
        const int j = wv * 48 + nt * 16 + l15;
        bf[nt] = *(const half8*)(smem + j * WSTRIDE + ((ks * 64 + l4 * 16) ^ ((j & 7) << 4)));
      }
#pragma unroll
      for (int mt = 0; mt < 4; ++mt)
#pragma unroll
        for (int nt = 0; nt < 3; ++nt)
          acc[mt][nt] = __builtin_amdgcn_mfma_f32_16x16x32_f16(a[mt], bf[nt], acc[mt][nt], 0, 0, 0);
      if (ks == 16)   // x-cols fragment: i_n = x @ w_ih_n^T
#pragma unroll
        for (int mt = 0; mt < 4; ++mt)
          accin[mt] = __builtin_amdgcn_mfma_f32_16x16x32_f16(a[mt], wihn, accin[mt], 0, 0, 0);
    }

    // ---- gates (fp32 state), write h(t+1) f16 to exchange
#pragma unroll
    for (int mt = 0; mt < 4; ++mt) {
#pragma unroll
      for (int q = 0; q < 4; ++q) {
        const int m = mt * 16 + l4 * 4 + q;                 // C/D: row=(lane>>4)*4+reg
        const float r = fast_sigmoid(acc[mt][0][q]);
        const float z = fast_sigmoid(acc[mt][1][q]);
        const float n = fast_tanh(accin[mt][q] + r * acc[mt][2][q]);
        const float hn = (1.0f - z) * n + z * hprev[mt][q];
        hprev[mt][q] = hn;
        bW[(crb + m) * KA + pcol] = (_Float16)hn;
      }
    }

    // ---- prefetch x_{t+1}
    if (t + 1 < TT && tid < 48) {
      const int r = tid / 12, i = tid - r * 12;
      const int row = crb + g * 4 + r;
      bW[row * KA + 512 + i] = (_Float16)hist[(size_t)row * (TT * II) + (t + 1) * II + i];
    }

    // ---- cluster barrier (cumulative counter, device scope)
    __threadfence();
    __syncthreads();
    if (tid == 0) {
      __hip_atomic_fetch_add(mybar, 1u, __ATOMIC_RELEASE, __HIP_MEMORY_SCOPE_AGENT);
      const unsigned tgt = (unsigned)GBLK * (unsigned)(t + 2);
      long spin = 0;
      while (!deadlock &&
             __hip_atomic_load(mybar, __ATOMIC_ACQUIRE, __HIP_MEMORY_SCOPE_AGENT) < tgt) {
        if (++spin > (1L << 24)) deadlock = 1;
      }
    }
    __syncthreads();
  }

  // ---- final logits (t = TT-1): h(TT) is in buf0 (TT even)
  {
    const _Float16* bA = buf0;
    const int rr  = 2 * wv + (l >> 5);
    const int row = crb + g * 4 + rr;
    const int jj  = (l >> 4) & 1;
    const _Float16* hp = bA + row * KA + l15 * 32;
    const float*    wo = w_out + jj * HH + l15 * 32;
    float s = 0.0f;
#pragma unroll
    for (int c8 = 0; c8 < 4; ++c8) {
      half8 hv = *(const half8*)(hp + c8 * 8);
#pragma unroll
      for (int i = 0; i < 8; ++i) s += (float)hv[i] * wo[c8 * 8 + i];
    }
#pragma unroll
    for (int off = 1; off < 16; off <<= 1) s += __shfl_xor(s, off);
    if (l15 == 0) out[((size_t)row * TT + (TT - 1)) * 2 + jj] = s + b_out[jj];
  }

  // ---- h_final (fp32 carried state)
#pragma unroll
  for (int mt = 0; mt < 4; ++mt)
#pragma unroll
    for (int q = 0; q < 4; ++q) {
      const int m = mt * 16 + l4 * 4 + q;
      out[(size_t)TB * TT * 2 + (size_t)(crb + m) * HH + pcol] = hprev[mt][q];
    }
}

extern "C" void kernel_launch(void* const* d_in, const int* in_sizes, int n_in,
                              void* d_out, int out_size, void* d_ws, size_t ws_size,
                              hipStream_t stream) {
  (void)in_sizes; (void)n_in; (void)out_size;
  if (ws_size < WS_USED) return;   // fail visibly (poison stays) rather than corrupt

  const float* hist  = (const float*)d_in[0];
  const float* w_ih  = (const float*)d_in[1];
  const float* w_hh  = (const float*)d_in[2];
  const float* w_out = (const float*)d_in[3];
  const float* b_out = (const float*)d_in[4];
  float* out = (float*)d_out;
  _Float16* buf = (_Float16*)d_ws;
  unsigned* bar = (unsigned*)((char*)d_ws + BAR_OFF);

  hipFuncSetAttribute((const void*)gru_persistent,
                      hipFuncAttributeMaxDynamicSharedMemorySize, LDSB);
  // zero exchange buffers (h0 = 0, pad cols) + barrier counters, every launch
  hipMemsetAsync(d_ws, 0, WS_USED, stream);

  void* args[] = {(void*)&hist, (void*)&w_ih, (void*)&w_hh, (void*)&w_out,
                  (void*)&b_out, (void*)&out, (void*)&buf, (void*)&bar};
  hipLaunchCooperativeKernel((const void*)gru_persistent, dim3(NB), dim3(NT),
                             args, (unsigned)LDSB, stream);
}

// Round 4
// 24731.418 us; speedup vs baseline: 2.3447x; 2.3447x over previous
//
#include <hip/hip_runtime.h>
#include <stdint.h>

// GRU scan, persistent cooperative kernel, round 4.
// = round 3 architecture with LDS cut to 128 KiB (160 KiB launch was failing):
//   n-gate W_hh slice lives in 64 VGPRs/wave (half8 wn[16]); LDS = 64 KiB W(r,z)
//   + 64 KiB A-tile. Fallback to plain launch if cooperative launch errors.
// 16 clusters x 64 batch rows; 16 blocks/cluster; block owns 32 hidden cols.
// Per step the 64KB cluster h-tile is staged global->LDS via global_load_lds
// (source pre-swizzled so linear copy + swizzled ds_read are conflict-free).

#define NB 256
#define NT 128
#define TB 1024
#define TT 2048
#define II 12
#define HH 512
#define GBLK 16
#define ROWS 64
#define NCL 16

#define HTILE_B (ROWS * HH * 2)               // 64 KiB per cluster per buffer
#define HBUF_B  ((size_t)NCL * HTILE_B)       // 1 MiB per buffer
#define XTILE_B (ROWS * 16 * 2)               // 2 KiB
#define XBUF_OFF ((size_t)2 * HBUF_B)
#define XBUF_B  ((size_t)NCL * XTILE_B)       // 32 KiB per buffer
#define BAR_OFF (XBUF_OFF + 2 * XBUF_B)
#define WS_USED (BAR_OFF + 1024)

#define LDS_W_B   (64 * 1024)                 // 64 KiB weights (r,z gates)
#define LDS_A_OFF LDS_W_B
#define LDSB      (LDS_W_B + ROWS * 1024)     // 131072 = 128 KiB exactly

#define GAS __attribute__((address_space(1)))
#define LAS __attribute__((address_space(3)))

typedef _Float16 half8 __attribute__((ext_vector_type(8)));
typedef float    f32x4 __attribute__((ext_vector_type(4)));

static __device__ __forceinline__ float fast_sigmoid(float x) {
  float e = exp2f(-1.44269504f * x);
  return __builtin_amdgcn_rcpf(1.0f + e);
}
static __device__ __forceinline__ float fast_tanh(float x) {
  float e = exp2f(2.88539008f * x);           // exp(2x)
  return 1.0f - 2.0f * __builtin_amdgcn_rcpf(1.0f + e);
}

__global__ void __launch_bounds__(NT, 1)
gru_persistent(const float* __restrict__ hist,
               const float* __restrict__ w_ih,
               const float* __restrict__ w_hh,
               const float* __restrict__ w_out,
               const float* __restrict__ b_out,
               float* __restrict__ out,
               uint8_t* __restrict__ ws)
{
  extern __shared__ char smem[];
  char* ldsW = smem;
  char* ldsA = smem + LDS_A_OFF;
  const int bid = blockIdx.x;
  const int c   = bid & 15;          // cluster
  const int g   = bid >> 4;          // block within cluster
  const int tid = threadIdx.x;
  const int wv  = tid >> 6;
  const int l   = tid & 63;
  const int l15 = l & 15;
  const int l4  = l >> 4;
  const int crb = c * ROWS;
  unsigned* mybar = (unsigned*)(ws + BAR_OFF) + c * 16;   // 64B-spaced

  // ---- W_hh (r,z) LDS fill: local row j = 32*wv_j + 16*gate + pl
  for (int idx = tid; idx < 64 * 64; idx += NT) {
    const int j   = idx >> 6;
    const int k8  = (idx & 63) * 8;
    const int wvj = j >> 5;
    const int gt  = (j >> 4) & 1;
    const int pl  = j & 15;
    const int R   = gt * HH + g * 32 + wvj * 16 + pl;
    half8 v;
#pragma unroll
    for (int i = 0; i < 8; ++i) v[i] = (_Float16)w_hh[(size_t)R * HH + k8 + i];
    *(half8*)(ldsW + j * 1024 + ((2 * k8) ^ ((j & 7) << 4))) = v;
  }

  // ---- n-gate W_hh slice in registers: B-fragment per ks (statically indexed)
  half8 wn[16];
  {
    const int Rn = 2 * HH + g * 32 + wv * 16 + l15;
#pragma unroll
    for (int ks = 0; ks < 16; ++ks)
#pragma unroll
      for (int i = 0; i < 8; ++i)
        wn[ks][i] = (_Float16)w_hh[(size_t)Rn * HH + ks * 32 + l4 * 8 + i];
  }

  // ---- w_ih register B-fragments for gates r,z,n (K window = x cols 0..31)
  half8 wih[3];
#pragma unroll
  for (int gt = 0; gt < 3; ++gt) {
    const int R = gt * HH + g * 32 + wv * 16 + l15;
#pragma unroll
    for (int i = 0; i < 8; ++i) {
      const int k = l4 * 8 + i;
      wih[gt][i] = (_Float16)((k < II) ? w_ih[R * II + k] : 0.0f);
    }
  }

  // ---- w_out hoisted to registers (logits never touch invalidated L2)
  const int jj = (l >> 4) & 1;
  float wor[32];
#pragma unroll
  for (int i = 0; i < 32; ++i) wor[i] = w_out[jj * HH + l15 * 32 + i];
  const float bo = b_out[jj];

  // ---- bootstrap x_0 (h-region of buffer 0 is memset-zero = h0)
  if (tid < 48) {
    const int r = tid / 12, i = tid - r * 12;
    const int lrow = g * 4 + r;
    *(_Float16*)(ws + XBUF_OFF + (size_t)c * XTILE_B + lrow * 32 + i * 2) =
        (_Float16)hist[(size_t)(crb + lrow) * (TT * II) + i];
  }

  float hprev[4][4];
#pragma unroll
  for (int mt = 0; mt < 4; ++mt)
#pragma unroll
    for (int q = 0; q < 4; ++q) hprev[mt][q] = 0.0f;

  const int pcol = g * 32 + wv * 16 + l15;
  int deadlock = 0;

  // ---- barrier 0
  __syncthreads();
  if (tid == 0) {
    __hip_atomic_fetch_add(mybar, 1u, __ATOMIC_RELEASE, __HIP_MEMORY_SCOPE_AGENT);
    long spin = 0;
    while (!deadlock &&
           __hip_atomic_load(mybar, __ATOMIC_RELAXED, __HIP_MEMORY_SCOPE_AGENT) < (unsigned)GBLK)
      if (++spin > (1L << 24)) deadlock = 1;
  }
  __syncthreads();
  (void)__hip_atomic_load(mybar, __ATOMIC_ACQUIRE, __HIP_MEMORY_SCOPE_AGENT);

  for (int t = 0; t <= TT; ++t) {
    // ---- stage cluster h-tile (64KB) -> LDS, linear copy of pre-swizzled data
    const uint8_t* hsrc = ws + ((t & 1) ? HBUF_B : 0) + (size_t)c * HTILE_B;
#pragma unroll
    for (int it = 0; it < 32; ++it)
      __builtin_amdgcn_global_load_lds(
          (const GAS uint32_t*)(hsrc + it * 2048 + tid * 16),
          (LAS uint32_t*)(ldsA + it * 2048 + tid * 16), 16, 0, 0);

    // ---- x fragments (cached global, tiny)
    half8 ax[4];
    if (t < TT) {
      const uint8_t* xb = ws + XBUF_OFF + ((t & 1) ? XBUF_B : 0) + (size_t)c * XTILE_B;
#pragma unroll
      for (int mt = 0; mt < 4; ++mt) {
        if (l4 < 2) ax[mt] = *(const half8*)(xb + (mt * 16 + l15) * 32 + l4 * 16);
        else        ax[mt] = (half8){0, 0, 0, 0, 0, 0, 0, 0};
      }
    }
    __syncthreads();   // drains vmcnt -> A-tile resident in LDS

    // ---- logits for step t-1 from LDS h(t)
    // lane l15 covers h elements l15*32 + c8*8 + [0..7]  -> byte l15*64 + c8*16
    if (t > 0) {
      const int rr   = 2 * wv + (l >> 5);
      const int lrow = g * 4 + rr;
      const int row  = crb + lrow;
      float s = 0.0f;
#pragma unroll
      for (int c8 = 0; c8 < 4; ++c8) {
        half8 hv = *(const half8*)(ldsA + lrow * 1024 +
                                   ((l15 * 64 + c8 * 16) ^ ((lrow & 7) << 4)));
#pragma unroll
        for (int i = 0; i < 8; ++i) s += (float)hv[i] * wor[c8 * 8 + i];
      }
#pragma unroll
      for (int off = 1; off < 16; off <<= 1) s += __shfl_xor(s, off);
      if (l15 == 0) out[((size_t)row * TT + (t - 1)) * 2 + jj] = s + bo;
    }
    if (t == TT) break;

    // ---- MFMA: acc[mt][r,z,n]; r,z B from LDS, n B from registers (wn)
    f32x4 acc[4][3];
    f32x4 accin[4];
#pragma unroll
    for (int mt = 0; mt < 4; ++mt) {
      accin[mt] = (f32x4){0.f, 0.f, 0.f, 0.f};
#pragma unroll
      for (int nt = 0; nt < 3; ++nt) acc[mt][nt] = (f32x4){0.f, 0.f, 0.f, 0.f};
    }
#pragma unroll
    for (int ks = 0; ks < 16; ++ks) {
      half8 a[4];
#pragma unroll
      for (int mt = 0; mt < 4; ++mt)
        a[mt] = *(const half8*)(ldsA + (mt * 16 + l15) * 1024 +
                                ((ks * 64 + l4 * 16) ^ ((l15 & 7) << 4)));
      half8 bf[2];
#pragma unroll
      for (int gt = 0; gt < 2; ++gt) {
        const int j = wv * 32 + gt * 16 + l15;
        bf[gt] = *(const half8*)(ldsW + j * 1024 +
                                 ((ks * 64 + l4 * 16) ^ ((l15 & 7) << 4)));
      }
#pragma unroll
      for (int mt = 0; mt < 4; ++mt) {
        acc[mt][0] = __builtin_amdgcn_mfma_f32_16x16x32_f16(a[mt], bf[0], acc[mt][0], 0, 0, 0);
        acc[mt][1] = __builtin_amdgcn_mfma_f32_16x16x32_f16(a[mt], bf[1], acc[mt][1], 0, 0, 0);
        acc[mt][2] = __builtin_amdgcn_mfma_f32_16x16x32_f16(a[mt], wn[ks], acc[mt][2], 0, 0, 0);
      }
    }
#pragma unroll
    for (int mt = 0; mt < 4; ++mt) {
      acc[mt][0] = __builtin_amdgcn_mfma_f32_16x16x32_f16(ax[mt], wih[0], acc[mt][0], 0, 0, 0);
      acc[mt][1] = __builtin_amdgcn_mfma_f32_16x16x32_f16(ax[mt], wih[1], acc[mt][1], 0, 0, 0);
      accin[mt]  = __builtin_amdgcn_mfma_f32_16x16x32_f16(ax[mt], wih[2], accin[mt], 0, 0, 0);
    }

    // ---- gates (fp32 state); h(t+1) stored PRE-SWIZZLED to exchange buffer
    uint8_t* hdst = ws + ((t & 1) ? 0 : HBUF_B) + (size_t)c * HTILE_B;
#pragma unroll
    for (int mt = 0; mt < 4; ++mt) {
#pragma unroll
      for (int q = 0; q < 4; ++q) {
        const int m = mt * 16 + l4 * 4 + q;
        const float r  = fast_sigmoid(acc[mt][0][q]);
        const float z  = fast_sigmoid(acc[mt][1][q]);
        const float n  = fast_tanh(accin[mt][q] + r * acc[mt][2][q]);
        const float hn = (1.0f - z) * n + z * hprev[mt][q];
        hprev[mt][q] = hn;
        *(_Float16*)(hdst + m * 1024 + ((pcol * 2) ^ ((m & 7) << 4))) = (_Float16)hn;
      }
    }

    // ---- prefetch x_{t+1} into other x half
    if (t + 1 < TT && tid < 48) {
      const int r = tid / 12, i = tid - r * 12;
      const int lrow = g * 4 + r;
      uint8_t* xbn = ws + XBUF_OFF + ((t & 1) ? 0 : XBUF_B) + (size_t)c * XTILE_B;
      *(_Float16*)(xbn + lrow * 32 + i * 2) =
          (_Float16)hist[(size_t)(crb + lrow) * (TT * II) + (size_t)(t + 1) * II + i];
    }

    // ---- cluster barrier: release add, RELAXED polls, single acquire
    __syncthreads();
    if (tid == 0) {
      __hip_atomic_fetch_add(mybar, 1u, __ATOMIC_RELEASE, __HIP_MEMORY_SCOPE_AGENT);
      const unsigned tgt = (unsigned)(GBLK * (t + 2));
      long spin = 0;
      while (!deadlock &&
             __hip_atomic_load(mybar, __ATOMIC_RELAXED, __HIP_MEMORY_SCOPE_AGENT) < tgt)
        if (++spin > (1L << 24)) deadlock = 1;
    }
    __syncthreads();
    (void)__hip_atomic_load(mybar, __ATOMIC_ACQUIRE, __HIP_MEMORY_SCOPE_AGENT);
  }

  // ---- h_final from fp32 carried state
#pragma unroll
  for (int mt = 0; mt < 4; ++mt)
#pragma unroll
    for (int q = 0; q < 4; ++q) {
      const int m = mt * 16 + l4 * 4 + q;
      out[(size_t)TB * TT * 2 + (size_t)(crb + m) * HH + pcol] = hprev[mt][q];
    }
}

extern "C" void kernel_launch(void* const* d_in, const int* in_sizes, int n_in,
                              void* d_out, int out_size, void* d_ws, size_t ws_size,
                              hipStream_t stream) {
  (void)in_sizes; (void)n_in; (void)out_size;
  if (ws_size < WS_USED) return;

  const float* hist  = (const float*)d_in[0];
  const float* w_ih  = (const float*)d_in[1];
  const float* w_hh  = (const float*)d_in[2];
  const float* w_out = (const float*)d_in[3];
  const float* b_out = (const float*)d_in[4];
  float* out = (float*)d_out;
  uint8_t* ws = (uint8_t*)d_ws;

  hipFuncSetAttribute((const void*)gru_persistent,
                      hipFuncAttributeMaxDynamicSharedMemorySize, LDSB);
  hipMemsetAsync(d_ws, 0, WS_USED, stream);   // h0 = 0, x pad, barrier counters

  void* args[] = {(void*)&hist, (void*)&w_ih, (void*)&w_hh, (void*)&w_out,
                  (void*)&b_out, (void*)&out, (void*)&ws};
  hipError_t e = hipLaunchCooperativeKernel((const void*)gru_persistent,
                                            dim3(NB), dim3(NT), args,
                                            (unsigned)LDSB, stream);
  if (e != hipSuccess) {
    // Fallback: plain launch. 256 blocks x 1/CU on 256 CUs co-reside; the
    // barrier spin has a deadlock bail-out so this cannot hang.
    gru_persistent<<<dim3(NB), dim3(NT), LDSB, stream>>>(
        hist, w_ih, w_hh, w_out, b_out, out, ws);
  }
}

// Round 5
// 14058.707 us; speedup vs baseline: 4.1247x; 1.7592x over previous
//
#include <hip/hip_runtime.h>
#include <stdint.h>

// GRU scan, persistent cooperative kernel, round 5.
// Round 4 + fence-free coherence: no agent release/acquire fences (those lower
// to whole-L2 wbl2/inv on multi-XCD gfx950 and cost ~9us/step). Instead:
//   - h stores:  __hip_atomic_store RELAXED/AGENT  -> global_store_short sc0 sc1
//   - h staging: global_load_lds aux=17 (SC0|SC1)  -> read-through, no-allocate
//   - flag:      relaxed agent fetch_add + relaxed polls (proven rounds 1-4)
// x is read directly from hist (read-only => coherent, L2-cacheable now that
// nothing invalidates L2). Split-phase staging overlaps MFMA rows 0-31 with
// the arrival of rows 32-63.

#define NB 256
#define NT 128
#define TB 1024
#define TT 2048
#define II 12
#define HH 512
#define GBLK 16
#define ROWS 64
#define NCL 16

#define HTILE_B (ROWS * HH * 2)               // 64 KiB per cluster per buffer
#define HBUF_B  ((size_t)NCL * HTILE_B)       // 1 MiB per buffer
#define BAR_OFF ((size_t)2 * HBUF_B)
#define WS_USED (BAR_OFF + 1024)

#define LDS_W_B   (64 * 1024)                 // 64 KiB weights (r,z gates)
#define LDSB      (LDS_W_B + ROWS * 1024)     // 131072 = 128 KiB

#define GAS __attribute__((address_space(1)))
#define LAS __attribute__((address_space(3)))

typedef _Float16 half8 __attribute__((ext_vector_type(8)));
typedef float    f32x4 __attribute__((ext_vector_type(4)));

static __device__ __forceinline__ float fast_sigmoid(float x) {
  float e = exp2f(-1.44269504f * x);
  return __builtin_amdgcn_rcpf(1.0f + e);
}
static __device__ __forceinline__ float fast_tanh(float x) {
  float e = exp2f(2.88539008f * x);           // exp(2x)
  return 1.0f - 2.0f * __builtin_amdgcn_rcpf(1.0f + e);
}

__global__ void __launch_bounds__(NT, 1)
gru_persistent(const float* __restrict__ hist,
               const float* __restrict__ w_ih,
               const float* __restrict__ w_hh,
               const float* __restrict__ w_out,
               const float* __restrict__ b_out,
               float* __restrict__ out,
               uint8_t* __restrict__ ws)
{
  extern __shared__ char smem[];
  char* ldsW = smem;
  char* ldsA = smem + LDS_W_B;
  const int bid = blockIdx.x;
  const int c   = bid & 15;          // cluster
  const int g   = bid >> 4;          // block within cluster
  const int tid = threadIdx.x;
  const int wv  = tid >> 6;
  const int l   = tid & 63;
  const int l15 = l & 15;
  const int l4  = l >> 4;
  const int crb = c * ROWS;
  unsigned* mybar = (unsigned*)(ws + BAR_OFF) + c * 16;   // 64B-spaced

  // ---- W_hh (r,z) LDS fill: local row j = 32*wv_j + 16*gate + pl
  for (int idx = tid; idx < 64 * 64; idx += NT) {
    const int j   = idx >> 6;
    const int k8  = (idx & 63) * 8;
    const int wvj = j >> 5;
    const int gt  = (j >> 4) & 1;
    const int pl  = j & 15;
    const int R   = gt * HH + g * 32 + wvj * 16 + pl;
    half8 v;
#pragma unroll
    for (int i = 0; i < 8; ++i) v[i] = (_Float16)w_hh[(size_t)R * HH + k8 + i];
    *(half8*)(ldsW + j * 1024 + ((2 * k8) ^ ((j & 7) << 4))) = v;
  }

  // ---- n-gate W_hh slice in registers (statically indexed)
  half8 wn[16];
  {
    const int Rn = 2 * HH + g * 32 + wv * 16 + l15;
#pragma unroll
    for (int ks = 0; ks < 16; ++ks)
#pragma unroll
      for (int i = 0; i < 8; ++i)
        wn[ks][i] = (_Float16)w_hh[(size_t)Rn * HH + ks * 32 + l4 * 8 + i];
  }

  // ---- w_ih register B-fragments for gates r,z,n (K window = x cols 0..31)
  half8 wih[3];
#pragma unroll
  for (int gt = 0; gt < 3; ++gt) {
    const int R = gt * HH + g * 32 + wv * 16 + l15;
#pragma unroll
    for (int i = 0; i < 8; ++i) {
      const int k = l4 * 8 + i;
      wih[gt][i] = (_Float16)((k < II) ? w_ih[R * II + k] : 0.0f);
    }
  }

  // ---- w_out in registers
  const int jj = (l >> 4) & 1;
  float wor[32];
#pragma unroll
  for (int i = 0; i < 32; ++i) wor[i] = w_out[jj * HH + l15 * 32 + i];
  const float bo = b_out[jj];

  float hprev[4][4];
#pragma unroll
  for (int mt = 0; mt < 4; ++mt)
#pragma unroll
    for (int q = 0; q < 4; ++q) hprev[mt][q] = 0.0f;

  const int pcol = g * 32 + wv * 16 + l15;
  int deadlock = 0;

  __syncthreads();   // W LDS ready (block-local; no cross-block dep at t=0)

  for (int t = 0; t <= TT; ++t) {
    // ---- x_t loads straight from hist (read-only, cacheable)
    f32x4 xa[4], xb4[4];
    if (t < TT) {
#pragma unroll
      for (int mt = 0; mt < 4; ++mt) {
        const float* xp = hist + (size_t)(crb + mt * 16 + l15) * (TT * II) + (size_t)t * II;
        xa[mt]  = (f32x4){0.f, 0.f, 0.f, 0.f};
        xb4[mt] = (f32x4){0.f, 0.f, 0.f, 0.f};
        if (l4 == 0)      { xa[mt] = *(const f32x4*)xp; xb4[mt] = *(const f32x4*)(xp + 4); }
        else if (l4 == 1) { xa[mt] = *(const f32x4*)(xp + 8); }
      }
    }
    __builtin_amdgcn_sched_barrier(0);

    // ---- stage cluster h-tile -> LDS, read-through (SC0|SC1 = 17), no-allocate
    const uint8_t* hsrc = ws + ((t & 1) ? HBUF_B : 0) + (size_t)c * HTILE_B;
#pragma unroll
    for (int it = 0; it < 16; ++it)          // rows 0-31
      __builtin_amdgcn_global_load_lds(
          (const GAS uint32_t*)(hsrc + it * 2048 + tid * 16),
          (LAS uint32_t*)(ldsA + it * 2048 + tid * 16), 16, 0, 17);
    __builtin_amdgcn_sched_barrier(0);
#pragma unroll
    for (int it = 16; it < 32; ++it)         // rows 32-63
      __builtin_amdgcn_global_load_lds(
          (const GAS uint32_t*)(hsrc + it * 2048 + tid * 16),
          (LAS uint32_t*)(ldsA + it * 2048 + tid * 16), 16, 0, 17);
    __builtin_amdgcn_sched_barrier(0);

    asm volatile("s_waitcnt vmcnt(16)" ::: "memory");   // x + rows 0-31 done
    __builtin_amdgcn_s_barrier();
    __builtin_amdgcn_sched_barrier(0);

    // ---- build x fragments
    half8 ax[4];
    if (t < TT) {
#pragma unroll
      for (int mt = 0; mt < 4; ++mt)
#pragma unroll
        for (int i = 0; i < 4; ++i) {
          ax[mt][i]     = (_Float16)xa[mt][i];
          ax[mt][4 + i] = (_Float16)xb4[mt][i];
        }
    }

    f32x4 acc[4][3];
    f32x4 accin[4];
#pragma unroll
    for (int mt = 0; mt < 4; ++mt) {
      accin[mt] = (f32x4){0.f, 0.f, 0.f, 0.f};
#pragma unroll
      for (int nt = 0; nt < 3; ++nt) acc[mt][nt] = (f32x4){0.f, 0.f, 0.f, 0.f};
    }

    if (t < TT) {   // x MFMAs (independent of staging)
#pragma unroll
      for (int mt = 0; mt < 4; ++mt) {
        acc[mt][0] = __builtin_amdgcn_mfma_f32_16x16x32_f16(ax[mt], wih[0], acc[mt][0], 0, 0, 0);
        acc[mt][1] = __builtin_amdgcn_mfma_f32_16x16x32_f16(ax[mt], wih[1], acc[mt][1], 0, 0, 0);
        accin[mt]  = __builtin_amdgcn_mfma_f32_16x16x32_f16(ax[mt], wih[2], accin[mt], 0, 0, 0);
      }
    }

    if (t < TT) {   // ---- phase 1: rows 0-31 (mt = 0,1)
#pragma unroll
      for (int ks = 0; ks < 16; ++ks) {
        const int ko = (ks * 64 + l4 * 16) ^ ((l15 & 7) << 4);
        half8 a0 = *(const half8*)(ldsA + (0 * 16 + l15) * 1024 + ko);
        half8 a1 = *(const half8*)(ldsA + (1 * 16 + l15) * 1024 + ko);
        half8 b0 = *(const half8*)(ldsW + (wv * 32 + 0 * 16 + l15) * 1024 + ko);
        half8 b1 = *(const half8*)(ldsW + (wv * 32 + 1 * 16 + l15) * 1024 + ko);
        acc[0][0] = __builtin_amdgcn_mfma_f32_16x16x32_f16(a0, b0, acc[0][0], 0, 0, 0);
        acc[0][1] = __builtin_amdgcn_mfma_f32_16x16x32_f16(a0, b1, acc[0][1], 0, 0, 0);
        acc[0][2] = __builtin_amdgcn_mfma_f32_16x16x32_f16(a0, wn[ks], acc[0][2], 0, 0, 0);
        acc[1][0] = __builtin_amdgcn_mfma_f32_16x16x32_f16(a1, b0, acc[1][0], 0, 0, 0);
        acc[1][1] = __builtin_amdgcn_mfma_f32_16x16x32_f16(a1, b1, acc[1][1], 0, 0, 0);
        acc[1][2] = __builtin_amdgcn_mfma_f32_16x16x32_f16(a1, wn[ks], acc[1][2], 0, 0, 0);
      }
    }

    asm volatile("s_waitcnt vmcnt(0)" ::: "memory");    // full tile resident
    __builtin_amdgcn_s_barrier();
    __builtin_amdgcn_sched_barrier(0);

    // ---- logits for step t-1 from LDS h(t)
    if (t > 0) {
      const int rr   = 2 * wv + (l >> 5);
      const int lrow = g * 4 + rr;
      const int row  = crb + lrow;
      float s = 0.0f;
#pragma unroll
      for (int c8 = 0; c8 < 4; ++c8) {
        half8 hv = *(const half8*)(ldsA + lrow * 1024 +
                                   ((l15 * 64 + c8 * 16) ^ ((lrow & 7) << 4)));
#pragma unroll
        for (int i = 0; i < 8; ++i) s += (float)hv[i] * wor[c8 * 8 + i];
      }
#pragma unroll
      for (int off = 1; off < 16; off <<= 1) s += __shfl_xor(s, off);
      if (l15 == 0) out[((size_t)row * TT + (t - 1)) * 2 + jj] = s + bo;
    }
    if (t == TT) break;

    // ---- phase 2: rows 32-63 (mt = 2,3)
#pragma unroll
    for (int ks = 0; ks < 16; ++ks) {
      const int ko = (ks * 64 + l4 * 16) ^ ((l15 & 7) << 4);
      half8 a2 = *(const half8*)(ldsA + (2 * 16 + l15) * 1024 + ko);
      half8 a3 = *(const half8*)(ldsA + (3 * 16 + l15) * 1024 + ko);
      half8 b0 = *(const half8*)(ldsW + (wv * 32 + 0 * 16 + l15) * 1024 + ko);
      half8 b1 = *(const half8*)(ldsW + (wv * 32 + 1 * 16 + l15) * 1024 + ko);
      acc[2][0] = __builtin_amdgcn_mfma_f32_16x16x32_f16(a2, b0, acc[2][0], 0, 0, 0);
      acc[2][1] = __builtin_amdgcn_mfma_f32_16x16x32_f16(a2, b1, acc[2][1], 0, 0, 0);
      acc[2][2] = __builtin_amdgcn_mfma_f32_16x16x32_f16(a2, wn[ks], acc[2][2], 0, 0, 0);
      acc[3][0] = __builtin_amdgcn_mfma_f32_16x16x32_f16(a3, b0, acc[3][0], 0, 0, 0);
      acc[3][1] = __builtin_amdgcn_mfma_f32_16x16x32_f16(a3, b1, acc[3][1], 0, 0, 0);
      acc[3][2] = __builtin_amdgcn_mfma_f32_16x16x32_f16(a3, wn[ks], acc[3][2], 0, 0, 0);
    }

    // ---- gates; h(t+1) stored pre-swizzled, write-through (RELAXED/AGENT)
    uint8_t* hdst = ws + ((t & 1) ? 0 : HBUF_B) + (size_t)c * HTILE_B;
#pragma unroll
    for (int mt = 0; mt < 4; ++mt) {
#pragma unroll
      for (int q = 0; q < 4; ++q) {
        const int m = mt * 16 + l4 * 4 + q;
        const float r  = fast_sigmoid(acc[mt][0][q]);
        const float z  = fast_sigmoid(acc[mt][1][q]);
        const float n  = fast_tanh(accin[mt][q] + r * acc[mt][2][q]);
        const float hn = (1.0f - z) * n + z * hprev[mt][q];
        hprev[mt][q] = hn;
        const unsigned short hu = __builtin_bit_cast(unsigned short, (_Float16)hn);
        __hip_atomic_store(
            (unsigned short*)(hdst + m * 1024 + ((pcol * 2) ^ ((m & 7) << 4))),
            hu, __ATOMIC_RELAXED, __HIP_MEMORY_SCOPE_AGENT);
      }
    }

    // ---- cluster barrier: drain stores, relaxed add, relaxed polls. No fences.
    asm volatile("s_waitcnt vmcnt(0)" ::: "memory");
    __syncthreads();
    if (tid == 0) {
      __hip_atomic_fetch_add(mybar, 1u, __ATOMIC_RELAXED, __HIP_MEMORY_SCOPE_AGENT);
      const unsigned tgt = (unsigned)(GBLK * (t + 1));
      long spin = 0;
      while (!deadlock &&
             __hip_atomic_load(mybar, __ATOMIC_RELAXED, __HIP_MEMORY_SCOPE_AGENT) < tgt)
        if (++spin > (1L << 24)) deadlock = 1;
    }
    __syncthreads();
  }

  // ---- h_final from fp32 carried state
#pragma unroll
  for (int mt = 0; mt < 4; ++mt)
#pragma unroll
    for (int q = 0; q < 4; ++q) {
      const int m = mt * 16 + l4 * 4 + q;
      out[(size_t)TB * TT * 2 + (size_t)(crb + m) * HH + pcol] = hprev[mt][q];
    }
}

extern "C" void kernel_launch(void* const* d_in, const int* in_sizes, int n_in,
                              void* d_out, int out_size, void* d_ws, size_t ws_size,
                              hipStream_t stream) {
  (void)in_sizes; (void)n_in; (void)out_size;
  if (ws_size < WS_USED) return;

  const float* hist  = (const float*)d_in[0];
  const float* w_ih  = (const float*)d_in[1];
  const float* w_hh  = (const float*)d_in[2];
  const float* w_out = (const float*)d_in[3];
  const float* b_out = (const float*)d_in[4];
  float* out = (float*)d_out;
  uint8_t* ws = (uint8_t*)d_ws;

  hipFuncSetAttribute((const void*)gru_persistent,
                      hipFuncAttributeMaxDynamicSharedMemorySize, LDSB);
  hipMemsetAsync(d_ws, 0, WS_USED, stream);   // h0 = 0, barrier counters

  void* args[] = {(void*)&hist, (void*)&w_ih, (void*)&w_hh, (void*)&w_out,
                  (void*)&b_out, (void*)&out, (void*)&ws};
  hipError_t e = hipLaunchCooperativeKernel((const void*)gru_persistent,
                                            dim3(NB), dim3(NT), args,
                                            (unsigned)LDSB, stream);
  if (e != hipSuccess) {
    // Fallback: plain launch. 256 blocks at 1/CU on 256 CUs co-reside; the
    // barrier spin has a deadlock bail-out so this cannot hang.
    gru_persistent<<<dim3(NB), dim3(NT), LDSB, stream>>>(
        hist, w_ih, w_hh, w_out, b_out, out, ws);
  }
}